// Round 4
// baseline (223.445 us; speedup 1.0000x reference)
//
#include <hip/hip_runtime.h>
#include <hip/hip_bf16.h>
#include <cstdint>

typedef __bf16 bf16;
typedef bf16 bf16x8 __attribute__((ext_vector_type(8)));
typedef float f32x4 __attribute__((ext_vector_type(4)));

#define NTOK 4096   // B*T
#define DLBL 512    // D_LABEL
#define NLAB 50

__device__ inline bf16x8 cvt8(float4 a, float4 b) {
  bf16x8 r;
  r[0] = (bf16)a.x; r[1] = (bf16)a.y; r[2] = (bf16)a.z; r[3] = (bf16)a.w;
  r[4] = (bf16)b.x; r[5] = (bf16)b.y; r[6] = (bf16)b.z; r[7] = (bf16)b.w;
  return r;
}

// async global->LDS, 16B per lane; LDS dest = wave-uniform base + lane*16
__device__ __forceinline__ void gl16(const bf16* g, void* l) {
  __builtin_amdgcn_global_load_lds(
      (const __attribute__((address_space(1))) void*)g,
      (__attribute__((address_space(3))) void*)l, 16, 0, 0);
}

// ---------------------------------------------------------------------------
// Kernel 1: convert biaffine W [50][512][512] f32 -> bf16 (same layout)
// ---------------------------------------------------------------------------
__global__ __launch_bounds__(256) void convW_k(const float* __restrict__ W,
                                               bf16* __restrict__ Wb) {
  int i = blockIdx.x * 256 + threadIdx.x;
  const float4* s = (const float4*)W + (size_t)i * 2;
  float4 a = s[0], b = s[1];
  *(bf16x8*)(Wb + (size_t)i * 8) = cvt8(a, b);
}

// ---------------------------------------------------------------------------
// Kernel 2: dep projection, TRANSPOSED output. LDS rows padded to 80B.
// ---------------------------------------------------------------------------
__global__ __launch_bounds__(256) void projA_k(const float* __restrict__ Wp,
                                               const float* __restrict__ X,
                                               const float* __restrict__ bv,
                                               bf16* __restrict__ outT) {
  __shared__ char lds[15360];
  char* ldsA = lds;           // [128 e][32 d] bf16, row stride 80B
  char* ldsB = lds + 10240;   // [64 tok][32 d] bf16, row stride 80B
  const int tid = threadIdx.x, l = tid & 63, w = tid >> 6;
  const int tokbase = blockIdx.y * 64;
  const int ebase   = blockIdx.x * 128;
  const int wr = w & 1, wc = w >> 1;
  f32x4 acc[4][2] = {};
  const int arow = tid >> 1, ahalf = tid & 1;
  const int brow = tid >> 2, bgr = tid & 3;
  const float* aS = Wp + (size_t)(ebase + arow) * 1024 + ahalf * 16;
  const float* bS = X  + (size_t)(tokbase + brow) * 1024 + bgr * 8;
  const int lo = (l & 15) * 80 + (l >> 4) * 16;
  for (int kb = 0; kb < 1024; kb += 32) {
    float4 a0 = *(const float4*)(aS + kb);
    float4 a1 = *(const float4*)(aS + kb + 4);
    float4 a2 = *(const float4*)(aS + kb + 8);
    float4 a3 = *(const float4*)(aS + kb + 12);
    float4 b0 = *(const float4*)(bS + kb);
    float4 b1 = *(const float4*)(bS + kb + 4);
    *(bf16x8*)(ldsA + arow * 80 + ahalf * 32)      = cvt8(a0, a1);
    *(bf16x8*)(ldsA + arow * 80 + ahalf * 32 + 16) = cvt8(a2, a3);
    *(bf16x8*)(ldsB + brow * 80 + bgr * 16)        = cvt8(b0, b1);
    __syncthreads();
    bf16x8 aF[4], bF[2];
#pragma unroll
    for (int i = 0; i < 4; ++i) aF[i] = *(bf16x8*)(ldsA + (wr * 64 + i * 16) * 80 + lo);
#pragma unroll
    for (int j = 0; j < 2; ++j) bF[j] = *(bf16x8*)(ldsB + (wc * 32 + j * 16) * 80 + lo);
#pragma unroll
    for (int i = 0; i < 4; ++i)
#pragma unroll
      for (int j = 0; j < 2; ++j)
        acc[i][j] = __builtin_amdgcn_mfma_f32_16x16x32_bf16(aF[i], bF[j], acc[i][j], 0, 0, 0);
    __syncthreads();
  }
#pragma unroll
  for (int i = 0; i < 4; ++i)
#pragma unroll
    for (int j = 0; j < 2; ++j)
#pragma unroll
      for (int r = 0; r < 4; ++r) {
        int eg = ebase + wr * 64 + i * 16 + (l >> 4) * 4 + r;
        int tg = tokbase + wc * 32 + j * 16 + (l & 15);
        outT[(size_t)eg * NTOK + tg] = (bf16)(acc[i][j][r] + bv[eg]);
      }
}

// ---------------------------------------------------------------------------
// Kernel 3: gathered head projection, natural output. Same 80B-pad fix.
// ---------------------------------------------------------------------------
__global__ __launch_bounds__(256) void projB_k(const float* __restrict__ head,
                                               const int* __restrict__ hidx,
                                               const float* __restrict__ Wp,
                                               const float* __restrict__ bv,
                                               bf16* __restrict__ selO) {
  __shared__ char lds[15360];
  char* ldsA = lds;           // [128 tok][32 d], stride 80
  char* ldsB = lds + 10240;   // [64 e][32 d], stride 80
  const int tid = threadIdx.x, l = tid & 63, w = tid >> 6;
  const int tokbase = blockIdx.y * 128;
  const int ebase   = blockIdx.x * 64;
  const int wr = w & 1, wc = w >> 1;
  f32x4 acc[4][2] = {};
  const int arow = tid >> 1, ahalf = tid & 1;
  const int brow = tid >> 2, bgr = tid & 3;
  const int flat = tokbase + arow;
  const int bb = flat >> 11;
  const int hv = hidx[flat];
  const float* aS = head + ((size_t)bb * 2049 + hv) * 1024 + ahalf * 16;
  const float* bS = Wp + (size_t)(ebase + brow) * 1024 + bgr * 8;
  const int lo = (l & 15) * 80 + (l >> 4) * 16;
  for (int kb = 0; kb < 1024; kb += 32) {
    float4 a0 = *(const float4*)(aS + kb);
    float4 a1 = *(const float4*)(aS + kb + 4);
    float4 a2 = *(const float4*)(aS + kb + 8);
    float4 a3 = *(const float4*)(aS + kb + 12);
    float4 b0 = *(const float4*)(bS + kb);
    float4 b1 = *(const float4*)(bS + kb + 4);
    *(bf16x8*)(ldsA + arow * 80 + ahalf * 32)      = cvt8(a0, a1);
    *(bf16x8*)(ldsA + arow * 80 + ahalf * 32 + 16) = cvt8(a2, a3);
    *(bf16x8*)(ldsB + brow * 80 + bgr * 16)        = cvt8(b0, b1);
    __syncthreads();
    bf16x8 aF[4], bF[2];
#pragma unroll
    for (int i = 0; i < 4; ++i) aF[i] = *(bf16x8*)(ldsA + (wr * 64 + i * 16) * 80 + lo);
#pragma unroll
    for (int j = 0; j < 2; ++j) bF[j] = *(bf16x8*)(ldsB + (wc * 32 + j * 16) * 80 + lo);
#pragma unroll
    for (int i = 0; i < 4; ++i)
#pragma unroll
      for (int j = 0; j < 2; ++j)
        acc[i][j] = __builtin_amdgcn_mfma_f32_16x16x32_bf16(aF[i], bF[j], acc[i][j], 0, 0, 0);
    __syncthreads();
  }
#pragma unroll
  for (int i = 0; i < 4; ++i)
#pragma unroll
    for (int j = 0; j < 2; ++j)
#pragma unroll
      for (int r = 0; r < 4; ++r) {
        int tg = tokbase + wr * 64 + i * 16 + (l >> 4) * 4 + r;
        int eg = ebase + wc * 32 + j * 16 + (l & 15);
        selO[(size_t)tg * DLBL + eg] = (bf16)(acc[i][j][r] + bv[eg]);
      }
}

// ---------------------------------------------------------------------------
// Kernel 4 v4: biaffine GEMM, 4-phase/K-tile counted-vmcnt pipeline (T3+T4+T5).
//   Tile 256d x 256tok, BK=64, K=512 (8 K-tiles), 8 waves (2d x 4tok),
//   wave tile 128d x 64tok = 8x4 frags. LDS 128KB = 2 buf x 4 regions of 16KB
//   (U/V x kk-half; 64B rows, swizzle chunk ^= (row>>1)&3, staged by 2 gl16).
//   Each phase: {ds_read subtile || 2 gl16 prefetch -> barrier -> 16 MFMA
//   (setprio) -> barrier}; vmcnt(8) twice per K-tile (tail: 8,4 then 0).
//   Prefetch lead 5-6 phases; loads stay in flight across barriers.
// ---------------------------------------------------------------------------
__global__ __launch_bounds__(512, 2) void biaff_k(const bf16* __restrict__ Wb,
                                                  const bf16* __restrict__ sel,
                                                  const bf16* __restrict__ depT,
                                                  float* __restrict__ parts) {
  __shared__ char lds[131072];
  const int tid = threadIdx.x, l = tid & 63, w = tid >> 6;

  // XCD-aware decode: 1600 = 8 xcd * 200; tok fastest within a combo so the
  // 16 tok-blocks of one (n,dz) run adjacently sharing the W panel in L2.
  const int lin = blockIdx.x;
  const int sw  = (lin & 7) * 200 + (lin >> 3);
  const int combo = sw >> 4;          // 0..99
  const int bx    = sw & 15;          // tok tile
  const int n  = combo >> 1;
  const int dz = combo & 1;
  const int tokbase = bx * 256;

  const int wd = w >> 2, wt = w & 3;  // wave tile: 128 d x 64 tok
  f32x4 acc[8][4] = {};

  // staging: lane covers row (l>>2) (+w*16, +128/call), stored chunk l&3;
  // source chunk pre-swizzled so LDS image has chunk ^= ((row>>1)&3)
  const int srow = l >> 2;
  const int schunk = (l & 3) ^ ((l >> 3) & 3);
  const bf16* aGb = Wb  + ((size_t)(n * DLBL + dz * 256 + w * 16 + srow)) * DLBL + schunk * 8;
  const bf16* bGb = sel + ((size_t)(tokbase + w * 16 + srow)) * DLBL + schunk * 8;

  // frag read bases (row = subtile + lq, chunk = lh ^ ((lq>>1)&3))
  const int lq = l & 15, lh = l >> 4;
  const int rchunk = lh ^ ((lq >> 1) & 3);
  const char* rdA = lds + (wd * 128 + lq) * 64 + rchunk * 16;
  const char* rdB = lds + 32768 + (wt * 64 + lq) * 64 + rchunk * 16;

#define STG_U(BUF, T, KK) do { \
    const bf16* s_ = aGb + (T) * 64 + (KK) * 32; \
    char* d_ = lds + (BUF) * 65536 + (KK) * 16384 + (w << 10); \
    gl16(s_, d_); gl16(s_ + 65536, d_ + 8192); \
  } while (0)
#define STG_V(BUF, T, KK) do { \
    const bf16* s_ = bGb + (T) * 64 + (KK) * 32; \
    char* d_ = lds + (BUF) * 65536 + 32768 + (KK) * 16384 + (w << 10); \
    gl16(s_, d_); gl16(s_ + 65536, d_ + 8192); \
  } while (0)
#define WAITV(N) asm volatile("s_waitcnt vmcnt(" #N ")" ::: "memory")
#define MM4(I, A) \
  acc[I][0] = __builtin_amdgcn_mfma_f32_16x16x32_bf16(A, b0, acc[I][0], 0, 0, 0); \
  acc[I][1] = __builtin_amdgcn_mfma_f32_16x16x32_bf16(A, b1, acc[I][1], 0, 0, 0); \
  acc[I][2] = __builtin_amdgcn_mfma_f32_16x16x32_bf16(A, b2, acc[I][2], 0, 0, 0); \
  acc[I][3] = __builtin_amdgcn_mfma_f32_16x16x32_bf16(A, b3, acc[I][3], 0, 0, 0);

#define TILE(T, CUR, NXT, DOS1, DOS2, WV1, WV3) do { \
    bf16x8 a0, a1, a2, a3, b0, b1, b2, b3; \
    /* ph0: kk0, i 0-3 */ \
    a0 = *(const bf16x8*)(rdA + (CUR) * 65536 + 0 * 1024); \
    a1 = *(const bf16x8*)(rdA + (CUR) * 65536 + 1 * 1024); \
    a2 = *(const bf16x8*)(rdA + (CUR) * 65536 + 2 * 1024); \
    a3 = *(const bf16x8*)(rdA + (CUR) * 65536 + 3 * 1024); \
    b0 = *(const bf16x8*)(rdB + (CUR) * 65536 + 0 * 1024); \
    b1 = *(const bf16x8*)(rdB + (CUR) * 65536 + 1 * 1024); \
    b2 = *(const bf16x8*)(rdB + (CUR) * 65536 + 2 * 1024); \
    b3 = *(const bf16x8*)(rdB + (CUR) * 65536 + 3 * 1024); \
    if (DOS1) { STG_U(NXT, (T) + 1, 1); } \
    __builtin_amdgcn_s_barrier(); \
    __builtin_amdgcn_s_setprio(1); \
    MM4(0, a0) MM4(1, a1) MM4(2, a2) MM4(3, a3) \
    __builtin_amdgcn_s_setprio(0); \
    __builtin_amdgcn_s_barrier(); \
    /* ph1: kk0, i 4-7 (bF reused) */ \
    a0 = *(const bf16x8*)(rdA + (CUR) * 65536 + 4 * 1024); \
    a1 = *(const bf16x8*)(rdA + (CUR) * 65536 + 5 * 1024); \
    a2 = *(const bf16x8*)(rdA + (CUR) * 65536 + 6 * 1024); \
    a3 = *(const bf16x8*)(rdA + (CUR) * 65536 + 7 * 1024); \
    if (DOS1) { STG_V(NXT, (T) + 1, 1); } \
    __builtin_amdgcn_s_barrier(); \
    __builtin_amdgcn_s_setprio(1); \
    MM4(4, a0) MM4(5, a1) MM4(6, a2) MM4(7, a3) \
    __builtin_amdgcn_s_setprio(0); \
    WV1; \
    __builtin_amdgcn_s_barrier(); \
    /* ph2: kk1, i 0-3 */ \
    a0 = *(const bf16x8*)(rdA + (CUR) * 65536 + 16384 + 0 * 1024); \
    a1 = *(const bf16x8*)(rdA + (CUR) * 65536 + 16384 + 1 * 1024); \
    a2 = *(const bf16x8*)(rdA + (CUR) * 65536 + 16384 + 2 * 1024); \
    a3 = *(const bf16x8*)(rdA + (CUR) * 65536 + 16384 + 3 * 1024); \
    b0 = *(const bf16x8*)(rdB + (CUR) * 65536 + 16384 + 0 * 1024); \
    b1 = *(const bf16x8*)(rdB + (CUR) * 65536 + 16384 + 1 * 1024); \
    b2 = *(const bf16x8*)(rdB + (CUR) * 65536 + 16384 + 2 * 1024); \
    b3 = *(const bf16x8*)(rdB + (CUR) * 65536 + 16384 + 3 * 1024); \
    if (DOS2) { STG_U(CUR, (T) + 2, 0); } \
    __builtin_amdgcn_s_barrier(); \
    __builtin_amdgcn_s_setprio(1); \
    MM4(0, a0) MM4(1, a1) MM4(2, a2) MM4(3, a3) \
    __builtin_amdgcn_s_setprio(0); \
    __builtin_amdgcn_s_barrier(); \
    /* ph3: kk1, i 4-7 */ \
    a0 = *(const bf16x8*)(rdA + (CUR) * 65536 + 16384 + 4 * 1024); \
    a1 = *(const bf16x8*)(rdA + (CUR) * 65536 + 16384 + 5 * 1024); \
    a2 = *(const bf16x8*)(rdA + (CUR) * 65536 + 16384 + 6 * 1024); \
    a3 = *(const bf16x8*)(rdA + (CUR) * 65536 + 16384 + 7 * 1024); \
    if (DOS2) { STG_V(CUR, (T) + 2, 0); } \
    __builtin_amdgcn_s_barrier(); \
    __builtin_amdgcn_s_setprio(1); \
    MM4(4, a0) MM4(5, a1) MM4(6, a2) MM4(7, a3) \
    __builtin_amdgcn_s_setprio(0); \
    WV3; \
    __builtin_amdgcn_s_barrier(); \
  } while (0)

  // prologue: (0).U0,V0,U1,V1, (1).U0,V0  (12 loads); certify (0).kk0
  STG_U(0, 0, 0); STG_V(0, 0, 0);
  STG_U(0, 0, 1); STG_V(0, 0, 1);
  STG_U(1, 1, 0); STG_V(1, 1, 0);
  WAITV(8);
  __builtin_amdgcn_s_barrier();

  TILE(0, 0, 1, 1, 1, WAITV(8), WAITV(8));
  TILE(1, 1, 0, 1, 1, WAITV(8), WAITV(8));
  TILE(2, 0, 1, 1, 1, WAITV(8), WAITV(8));
  TILE(3, 1, 0, 1, 1, WAITV(8), WAITV(8));
  TILE(4, 0, 1, 1, 1, WAITV(8), WAITV(8));
  TILE(5, 1, 0, 1, 1, WAITV(8), WAITV(8));
  TILE(6, 0, 1, 1, 0, WAITV(8), WAITV(4));
  TILE(7, 1, 0, 0, 0, WAITV(0), ((void)0));

#undef TILE
#undef MM4
#undef WAITV
#undef STG_U
#undef STG_V

  // ---- epilogue: H[d,t] * depT[d,t], reduce over the wave's 128 d ----
  const bf16* dT = depT + (size_t)(dz * 256 + wd * 128) * NTOK;
  float p[4] = {0.f, 0.f, 0.f, 0.f};
#pragma unroll
  for (int j = 0; j < 4; ++j) {
    const int tg = tokbase + wt * 64 + j * 16 + lq;
#pragma unroll
    for (int i = 0; i < 8; ++i)
#pragma unroll
      for (int r = 0; r < 4; ++r)
        p[j] += acc[i][j][r] * (float)dT[(size_t)(i * 16 + lh * 4 + r) * NTOK + tg];
  }
#pragma unroll
  for (int j = 0; j < 4; ++j) {
    p[j] += __shfl_xor(p[j], 16);
    p[j] += __shfl_xor(p[j], 32);
  }
  if (l < 16) {
#pragma unroll
    for (int j = 0; j < 4; ++j) {
      int tg = tokbase + wt * 64 + j * 16 + l;
      parts[(size_t)(dz * 2 + wd) * 204800 + (size_t)tg * NLAB + n] = p[j];
    }
  }
}

// ---------------------------------------------------------------------------
// Kernel 5: sum the 4 d-partials + bias -> logits [4096][50] f32
// ---------------------------------------------------------------------------
__global__ __launch_bounds__(256) void fin_k(const float* __restrict__ parts,
                                             const float* __restrict__ bias,
                                             float* __restrict__ out) {
  int i = blockIdx.x * 256 + threadIdx.x;
  float v = 0.f;
#pragma unroll
  for (int q = 0; q < 4; ++q) v += parts[(size_t)q * 204800 + i];
  out[i] = v + bias[i % NLAB];
}

// ---------------------------------------------------------------------------
extern "C" void kernel_launch(void* const* d_in, const int* in_sizes, int n_in,
                              void* d_out, int out_size, void* d_ws, size_t ws_size,
                              hipStream_t stream) {
  const float* dep    = (const float*)d_in[0];
  const float* head   = (const float*)d_in[1];
  const int*   hidx   = (const int*)d_in[2];
  const float* dep_W  = (const float*)d_in[4];
  const float* dep_b  = (const float*)d_in[5];
  const float* head_W = (const float*)d_in[6];
  const float* head_b = (const float*)d_in[7];
  const float* W      = (const float*)d_in[8];
  const float* bias   = (const float*)d_in[9];
  float* out = (float*)d_out;

  char* ws = (char*)d_ws;
  bf16*  Wb    = (bf16*)(ws);
  bf16*  depT  = (bf16*)(ws + 26214400);
  bf16*  selB  = (bf16*)(ws + 30408704);
  float* parts = (float*)(ws + 34603008);
  if (ws_size < (size_t)37879808) return;

  hipLaunchKernelGGL(convW_k, dim3(6400), dim3(256), 0, stream, W, Wb);
  hipLaunchKernelGGL(projA_k, dim3(4, 64), dim3(256), 0, stream, dep_W, dep, dep_b, depT);
  hipLaunchKernelGGL(projB_k, dim3(8, 32), dim3(256), 0, stream, head, hidx, head_W, head_b, selB);
  hipLaunchKernelGGL(biaff_k, dim3(1600), dim3(512), 0, stream, Wb, selB, depT, parts);
  hipLaunchKernelGGL(fin_k, dim3(800), dim3(256), 0, stream, parts, bias, out);
}

// Round 5
// 194.217 us; speedup vs baseline: 1.1505x; 1.1505x over previous
//
#include <hip/hip_runtime.h>
#include <hip/hip_bf16.h>
#include <cstdint>

typedef __bf16 bf16;
typedef bf16 bf16x8 __attribute__((ext_vector_type(8)));
typedef float f32x4 __attribute__((ext_vector_type(4)));

#define NTOK 4096   // B*T
#define DLBL 512    // D_LABEL
#define NLAB 50

__device__ inline bf16x8 cvt8(float4 a, float4 b) {
  bf16x8 r;
  r[0] = (bf16)a.x; r[1] = (bf16)a.y; r[2] = (bf16)a.z; r[3] = (bf16)a.w;
  r[4] = (bf16)b.x; r[5] = (bf16)b.y; r[6] = (bf16)b.z; r[7] = (bf16)b.w;
  return r;
}

// async global->LDS, 16B per lane; LDS dest = wave-uniform base + lane*16
__device__ __forceinline__ void gl16(const bf16* g, void* l) {
  __builtin_amdgcn_global_load_lds(
      (const __attribute__((address_space(1))) void*)g,
      (__attribute__((address_space(3))) void*)l, 16, 0, 0);
}

// ---------------------------------------------------------------------------
// Kernel 1: convert biaffine W [50][512][512] f32 -> bf16 (same layout)
// ---------------------------------------------------------------------------
__global__ __launch_bounds__(256) void convW_k(const float* __restrict__ W,
                                               bf16* __restrict__ Wb) {
  int i = blockIdx.x * 256 + threadIdx.x;
  const float4* s = (const float4*)W + (size_t)i * 2;
  float4 a = s[0], b = s[1];
  *(bf16x8*)(Wb + (size_t)i * 8) = cvt8(a, b);
}

// ---------------------------------------------------------------------------
// Kernel 2: dep projection, TRANSPOSED output. LDS rows padded to 80B.
// ---------------------------------------------------------------------------
__global__ __launch_bounds__(256) void projA_k(const float* __restrict__ Wp,
                                               const float* __restrict__ X,
                                               const float* __restrict__ bv,
                                               bf16* __restrict__ outT) {
  __shared__ char lds[15360];
  char* ldsA = lds;           // [128 e][32 d] bf16, row stride 80B
  char* ldsB = lds + 10240;   // [64 tok][32 d] bf16, row stride 80B
  const int tid = threadIdx.x, l = tid & 63, w = tid >> 6;
  const int tokbase = blockIdx.y * 64;
  const int ebase   = blockIdx.x * 128;
  const int wr = w & 1, wc = w >> 1;
  f32x4 acc[4][2] = {};
  const int arow = tid >> 1, ahalf = tid & 1;
  const int brow = tid >> 2, bgr = tid & 3;
  const float* aS = Wp + (size_t)(ebase + arow) * 1024 + ahalf * 16;
  const float* bS = X  + (size_t)(tokbase + brow) * 1024 + bgr * 8;
  const int lo = (l & 15) * 80 + (l >> 4) * 16;
  for (int kb = 0; kb < 1024; kb += 32) {
    float4 a0 = *(const float4*)(aS + kb);
    float4 a1 = *(const float4*)(aS + kb + 4);
    float4 a2 = *(const float4*)(aS + kb + 8);
    float4 a3 = *(const float4*)(aS + kb + 12);
    float4 b0 = *(const float4*)(bS + kb);
    float4 b1 = *(const float4*)(bS + kb + 4);
    *(bf16x8*)(ldsA + arow * 80 + ahalf * 32)      = cvt8(a0, a1);
    *(bf16x8*)(ldsA + arow * 80 + ahalf * 32 + 16) = cvt8(a2, a3);
    *(bf16x8*)(ldsB + brow * 80 + bgr * 16)        = cvt8(b0, b1);
    __syncthreads();
    bf16x8 aF[4], bF[2];
#pragma unroll
    for (int i = 0; i < 4; ++i) aF[i] = *(bf16x8*)(ldsA + (wr * 64 + i * 16) * 80 + lo);
#pragma unroll
    for (int j = 0; j < 2; ++j) bF[j] = *(bf16x8*)(ldsB + (wc * 32 + j * 16) * 80 + lo);
#pragma unroll
    for (int i = 0; i < 4; ++i)
#pragma unroll
      for (int j = 0; j < 2; ++j)
        acc[i][j] = __builtin_amdgcn_mfma_f32_16x16x32_bf16(aF[i], bF[j], acc[i][j], 0, 0, 0);
    __syncthreads();
  }
#pragma unroll
  for (int i = 0; i < 4; ++i)
#pragma unroll
    for (int j = 0; j < 2; ++j)
#pragma unroll
      for (int r = 0; r < 4; ++r) {
        int eg = ebase + wr * 64 + i * 16 + (l >> 4) * 4 + r;
        int tg = tokbase + wc * 32 + j * 16 + (l & 15);
        outT[(size_t)eg * NTOK + tg] = (bf16)(acc[i][j][r] + bv[eg]);
      }
}

// ---------------------------------------------------------------------------
// Kernel 3: gathered head projection, natural output. Same 80B-pad fix.
// ---------------------------------------------------------------------------
__global__ __launch_bounds__(256) void projB_k(const float* __restrict__ head,
                                               const int* __restrict__ hidx,
                                               const float* __restrict__ Wp,
                                               const float* __restrict__ bv,
                                               bf16* __restrict__ selO) {
  __shared__ char lds[15360];
  char* ldsA = lds;           // [128 tok][32 d], stride 80
  char* ldsB = lds + 10240;   // [64 e][32 d], stride 80
  const int tid = threadIdx.x, l = tid & 63, w = tid >> 6;
  const int tokbase = blockIdx.y * 128;
  const int ebase   = blockIdx.x * 64;
  const int wr = w & 1, wc = w >> 1;
  f32x4 acc[4][2] = {};
  const int arow = tid >> 1, ahalf = tid & 1;
  const int brow = tid >> 2, bgr = tid & 3;
  const int flat = tokbase + arow;
  const int bb = flat >> 11;
  const int hv = hidx[flat];
  const float* aS = head + ((size_t)bb * 2049 + hv) * 1024 + ahalf * 16;
  const float* bS = Wp + (size_t)(ebase + brow) * 1024 + bgr * 8;
  const int lo = (l & 15) * 80 + (l >> 4) * 16;
  for (int kb = 0; kb < 1024; kb += 32) {
    float4 a0 = *(const float4*)(aS + kb);
    float4 a1 = *(const float4*)(aS + kb + 4);
    float4 a2 = *(const float4*)(aS + kb + 8);
    float4 a3 = *(const float4*)(aS + kb + 12);
    float4 b0 = *(const float4*)(bS + kb);
    float4 b1 = *(const float4*)(bS + kb + 4);
    *(bf16x8*)(ldsA + arow * 80 + ahalf * 32)      = cvt8(a0, a1);
    *(bf16x8*)(ldsA + arow * 80 + ahalf * 32 + 16) = cvt8(a2, a3);
    *(bf16x8*)(ldsB + brow * 80 + bgr * 16)        = cvt8(b0, b1);
    __syncthreads();
    bf16x8 aF[4], bF[2];
#pragma unroll
    for (int i = 0; i < 4; ++i) aF[i] = *(bf16x8*)(ldsA + (wr * 64 + i * 16) * 80 + lo);
#pragma unroll
    for (int j = 0; j < 2; ++j) bF[j] = *(bf16x8*)(ldsB + (wc * 32 + j * 16) * 80 + lo);
#pragma unroll
    for (int i = 0; i < 4; ++i)
#pragma unroll
      for (int j = 0; j < 2; ++j)
        acc[i][j] = __builtin_amdgcn_mfma_f32_16x16x32_bf16(aF[i], bF[j], acc[i][j], 0, 0, 0);
    __syncthreads();
  }
#pragma unroll
  for (int i = 0; i < 4; ++i)
#pragma unroll
    for (int j = 0; j < 2; ++j)
#pragma unroll
      for (int r = 0; r < 4; ++r) {
        int tg = tokbase + wr * 64 + i * 16 + (l >> 4) * 4 + r;
        int eg = ebase + wc * 32 + j * 16 + (l & 15);
        selO[(size_t)tg * DLBL + eg] = (bf16)(acc[i][j][r] + bv[eg]);
      }
}

// ---------------------------------------------------------------------------
// Kernel 4 v5: biaffine GEMM, 128d x 256tok tile, BK=32, TRIPLE-buffered
// 72KB LDS -> 2 blocks/CU (implicit inter-block overlap, m114), counted
// vmcnt(3) + single barrier per K-tile, 2-tile prefetch lead, setprio MFMA.
//   8 waves (2d x 4tok), wave tile 64d x 64tok = 4x4 frags, 16 K-tiles.
//   Per K-tile loads: A 1 gl16/wave, B 2 gl16/wave (3 total).
//   Phase t: {8 ds_read | stage tile t+2 -> buf[(t+2)%3] | 16 MFMA |
//             vmcnt(3) certifies tile t+1 | barrier}.
//   XCD map (round-3 proven): xcd owns 25 combos (W slice 3.2MB L2-resident),
//   combo fastest, tok slow.
// ---------------------------------------------------------------------------
__global__ __launch_bounds__(512, 4) void biaff_k(const bf16* __restrict__ Wb,
                                                  const bf16* __restrict__ sel,
                                                  const bf16* __restrict__ depT,
                                                  float* __restrict__ parts) {
  __shared__ char lds[73728];          // 3 x (A 8KB + B 16KB)
  const int tid = threadIdx.x, l = tid & 63, w = tid >> 6;

  // bijective XCD-aware decode: 3200 = 8 xcd * (25 combos * 16 tok), combo fast
  const int lin = blockIdx.x;
  const int xcd = lin & 7, idx = lin >> 3;   // idx 0..399
  const int sub = idx % 25;                  // fast
  const int bx  = idx / 25;                  // slow: tok tile 0..15
  const int combo = xcd * 25 + sub;          // 0..199
  const int n  = combo % 50;
  const int dz = combo / 50;                 // 0..3
  const int tokbase = bx * 256;
  const int dbase   = dz * 128;

  const int wd = w >> 2, wt = w & 3;         // wave tile: 64 d x 64 tok
  f32x4 acc[4][4] = {};

  // staging: lane -> row l>>2, stored chunk l&3; source chunk pre-swizzled
  // so the LDS image carries chunk ^= ((row>>1)&3)
  const int srow = l >> 2;
  const int schunk = ((l & 3) ^ ((l >> 3) & 3)) * 8;
  const bf16* aG = Wb  + ((size_t)(n * DLBL + dbase + w * 16 + srow)) * DLBL + schunk;
  const bf16* bG = sel + ((size_t)(tokbase + w * 32 + srow)) * DLBL + schunk;
  const int aOff = w * 1024;                 // w*16 rows * 64B
  const int bOff = 8192 + w * 2048;          // w*32 rows * 64B

  // frag reads: row = sub + lq, chunk = lh ^ ((lq>>1)&3)  (conflict-free, measured)
  const int lq = l & 15, lh = l >> 4;
  const int ro = lh ^ ((lq >> 1) & 3);
  const char* rdA = lds + (wd * 64 + lq) * 64 + ro * 16;
  const char* rdB = lds + 8192 + (wt * 64 + lq) * 64 + ro * 16;

#define STG(T) do { \
    const bf16* a_ = aG + (T) * 32; \
    const bf16* b_ = bG + (T) * 32; \
    char* la_ = lds + ((T) % 3) * 24576 + aOff; \
    char* lb_ = lds + ((T) % 3) * 24576 + bOff; \
    gl16(a_, la_); \
    gl16(b_, lb_); \
    gl16(b_ + 16 * DLBL, lb_ + 1024); \
  } while (0)
#define WAITV(N) asm volatile("s_waitcnt vmcnt(" #N ")" ::: "memory")
#define PHASE(T, DOSTG, DOWV3, DOWV0, DOBAR) do { \
    const char* cA = rdA + ((T) % 3) * 24576; \
    const char* cB = rdB + ((T) % 3) * 24576; \
    bf16x8 aF[4], bF[4]; \
    aF[0] = *(const bf16x8*)(cA + 0 * 1024); \
    aF[1] = *(const bf16x8*)(cA + 1 * 1024); \
    aF[2] = *(const bf16x8*)(cA + 2 * 1024); \
    aF[3] = *(const bf16x8*)(cA + 3 * 1024); \
    bF[0] = *(const bf16x8*)(cB + 0 * 1024); \
    bF[1] = *(const bf16x8*)(cB + 1 * 1024); \
    bF[2] = *(const bf16x8*)(cB + 2 * 1024); \
    bF[3] = *(const bf16x8*)(cB + 3 * 1024); \
    if (DOSTG) STG((T) + 2); \
    __builtin_amdgcn_s_setprio(1); \
    _Pragma("unroll") \
    for (int i = 0; i < 4; ++i) \
      _Pragma("unroll") \
      for (int j = 0; j < 4; ++j) \
        acc[i][j] = __builtin_amdgcn_mfma_f32_16x16x32_bf16(aF[i], bF[j], acc[i][j], 0, 0, 0); \
    __builtin_amdgcn_s_setprio(0); \
    if (DOWV3) WAITV(3); \
    if (DOWV0) WAITV(0); \
    if (DOBAR) __builtin_amdgcn_s_barrier(); \
  } while (0)

  // prologue: stage tiles 0,1 (6 loads); certify tile 0 (drain to 3)
  STG(0); STG(1);
  WAITV(3);
  __builtin_amdgcn_s_barrier();

  PHASE(0, 1, 1, 0, 1);  PHASE(1, 1, 1, 0, 1);  PHASE(2, 1, 1, 0, 1);
  PHASE(3, 1, 1, 0, 1);  PHASE(4, 1, 1, 0, 1);  PHASE(5, 1, 1, 0, 1);
  PHASE(6, 1, 1, 0, 1);  PHASE(7, 1, 1, 0, 1);  PHASE(8, 1, 1, 0, 1);
  PHASE(9, 1, 1, 0, 1);  PHASE(10, 1, 1, 0, 1); PHASE(11, 1, 1, 0, 1);
  PHASE(12, 1, 1, 0, 1); PHASE(13, 1, 1, 0, 1);
  PHASE(14, 0, 0, 1, 1);                      // no stage; certify tile 15
  PHASE(15, 0, 0, 0, 0);                      // final tile, no sync needed

#undef PHASE
#undef WAITV
#undef STG

  // ---- epilogue: H[d,t] * depT[d,t], reduce over the wave's 64 d ----
  float p[4] = {0.f, 0.f, 0.f, 0.f};
#pragma unroll
  for (int j = 0; j < 4; ++j) {
    const int tg = tokbase + wt * 64 + j * 16 + lq;
#pragma unroll
    for (int i = 0; i < 4; ++i)
#pragma unroll
      for (int r = 0; r < 4; ++r) {
        int dg = dbase + wd * 64 + i * 16 + lh * 4 + r;
        p[j] += acc[i][j][r] * (float)depT[(size_t)dg * NTOK + tg];
      }
  }
#pragma unroll
  for (int j = 0; j < 4; ++j) {
    p[j] += __shfl_xor(p[j], 16);
    p[j] += __shfl_xor(p[j], 32);
  }
  if (l < 16) {
#pragma unroll
    for (int j = 0; j < 4; ++j) {
      int tg = tokbase + wt * 64 + j * 16 + l;
      parts[(size_t)(dz * 2 + wd) * 204800 + (size_t)tg * NLAB + n] = p[j];
    }
  }
}

// ---------------------------------------------------------------------------
// Kernel 5: sum the 8 d-partials + bias -> logits [4096][50] f32
// ---------------------------------------------------------------------------
__global__ __launch_bounds__(256) void fin_k(const float* __restrict__ parts,
                                             const float* __restrict__ bias,
                                             float* __restrict__ out) {
  int i = blockIdx.x * 256 + threadIdx.x;
  float v = 0.f;
#pragma unroll
  for (int q = 0; q < 8; ++q) v += parts[(size_t)q * 204800 + i];
  out[i] = v + bias[i % NLAB];
}

// ---------------------------------------------------------------------------
extern "C" void kernel_launch(void* const* d_in, const int* in_sizes, int n_in,
                              void* d_out, int out_size, void* d_ws, size_t ws_size,
                              hipStream_t stream) {
  const float* dep    = (const float*)d_in[0];
  const float* head   = (const float*)d_in[1];
  const int*   hidx   = (const int*)d_in[2];
  const float* dep_W  = (const float*)d_in[4];
  const float* dep_b  = (const float*)d_in[5];
  const float* head_W = (const float*)d_in[6];
  const float* head_b = (const float*)d_in[7];
  const float* W      = (const float*)d_in[8];
  const float* bias   = (const float*)d_in[9];
  float* out = (float*)d_out;

  char* ws = (char*)d_ws;
  bf16*  Wb    = (bf16*)(ws);
  bf16*  depT  = (bf16*)(ws + 26214400);
  bf16*  selB  = (bf16*)(ws + 30408704);
  float* parts = (float*)(ws + 34603008);
  if (ws_size < (size_t)41156608) return;

  hipLaunchKernelGGL(convW_k, dim3(6400), dim3(256), 0, stream, W, Wb);
  hipLaunchKernelGGL(projA_k, dim3(4, 64), dim3(256), 0, stream, dep_W, dep, dep_b, depT);
  hipLaunchKernelGGL(projB_k, dim3(8, 32), dim3(256), 0, stream, head, hidx, head_W, head_b, selB);
  hipLaunchKernelGGL(biaff_k, dim3(3200), dim3(512), 0, stream, Wb, selB, depT, parts);
  hipLaunchKernelGGL(fin_k, dim3(800), dim3(256), 0, stream, parts, bias, out);
}

// Round 6
// 163.273 us; speedup vs baseline: 1.3685x; 1.1895x over previous
//
#include <hip/hip_runtime.h>
#include <hip/hip_bf16.h>
#include <cstdint>

typedef __bf16 bf16;
typedef bf16 bf16x8 __attribute__((ext_vector_type(8)));
typedef float f32x4 __attribute__((ext_vector_type(4)));

#define NTOK 4096   // B*T
#define DLBL 512    // D_LABEL
#define NLAB 50

__device__ inline bf16x8 cvt8(float4 a, float4 b) {
  bf16x8 r;
  r[0] = (bf16)a.x; r[1] = (bf16)a.y; r[2] = (bf16)a.z; r[3] = (bf16)a.w;
  r[4] = (bf16)b.x; r[5] = (bf16)b.y; r[6] = (bf16)b.z; r[7] = (bf16)b.w;
  return r;
}

// async global->LDS, 16B per lane; LDS dest = wave-uniform base + lane*16
__device__ __forceinline__ void gl16(const bf16* g, void* l) {
  __builtin_amdgcn_global_load_lds(
      (const __attribute__((address_space(1))) void*)g,
      (__attribute__((address_space(3))) void*)l, 16, 0, 0);
}

// ---------------------------------------------------------------------------
// Fused prep kernel: blocks [0,256) projA, [256,512) projB, [512,6912) convW.
// projA/projB first so the compute-bound parts start early; convW (pure BW)
// fills the remaining issue slots concurrently.
// ---------------------------------------------------------------------------
__device__ void projA_body(int bidx, const float* __restrict__ Wp,
                           const float* __restrict__ X,
                           const float* __restrict__ bv,
                           bf16* __restrict__ outT, char* lds) {
  char* ldsA = lds;           // [128 e][32 d] bf16, row stride 80B
  char* ldsB = lds + 10240;   // [64 tok][32 d] bf16, row stride 80B
  const int tid = threadIdx.x, l = tid & 63, w = tid >> 6;
  const int tokbase = (bidx >> 2) * 64;
  const int ebase   = (bidx & 3) * 128;
  const int wr = w & 1, wc = w >> 1;
  f32x4 acc[4][2] = {};
  const int arow = tid >> 1, ahalf = tid & 1;
  const int brow = tid >> 2, bgr = tid & 3;
  const float* aS = Wp + (size_t)(ebase + arow) * 1024 + ahalf * 16;
  const float* bS = X  + (size_t)(tokbase + brow) * 1024 + bgr * 8;
  const int lo = (l & 15) * 80 + (l >> 4) * 16;
  for (int kb = 0; kb < 1024; kb += 32) {
    float4 a0 = *(const float4*)(aS + kb);
    float4 a1 = *(const float4*)(aS + kb + 4);
    float4 a2 = *(const float4*)(aS + kb + 8);
    float4 a3 = *(const float4*)(aS + kb + 12);
    float4 b0 = *(const float4*)(bS + kb);
    float4 b1 = *(const float4*)(bS + kb + 4);
    *(bf16x8*)(ldsA + arow * 80 + ahalf * 32)      = cvt8(a0, a1);
    *(bf16x8*)(ldsA + arow * 80 + ahalf * 32 + 16) = cvt8(a2, a3);
    *(bf16x8*)(ldsB + brow * 80 + bgr * 16)        = cvt8(b0, b1);
    __syncthreads();
    bf16x8 aF[4], bF[2];
#pragma unroll
    for (int i = 0; i < 4; ++i) aF[i] = *(bf16x8*)(ldsA + (wr * 64 + i * 16) * 80 + lo);
#pragma unroll
    for (int j = 0; j < 2; ++j) bF[j] = *(bf16x8*)(ldsB + (wc * 32 + j * 16) * 80 + lo);
#pragma unroll
    for (int i = 0; i < 4; ++i)
#pragma unroll
      for (int j = 0; j < 2; ++j)
        acc[i][j] = __builtin_amdgcn_mfma_f32_16x16x32_bf16(aF[i], bF[j], acc[i][j], 0, 0, 0);
    __syncthreads();
  }
#pragma unroll
  for (int i = 0; i < 4; ++i)
#pragma unroll
    for (int j = 0; j < 2; ++j)
#pragma unroll
      for (int r = 0; r < 4; ++r) {
        int eg = ebase + wr * 64 + i * 16 + (l >> 4) * 4 + r;
        int tg = tokbase + wc * 32 + j * 16 + (l & 15);
        outT[(size_t)eg * NTOK + tg] = (bf16)(acc[i][j][r] + bv[eg]);
      }
}

__device__ void projB_body(int bidx, const float* __restrict__ head,
                           const int* __restrict__ hidx,
                           const float* __restrict__ Wp,
                           const float* __restrict__ bv,
                           bf16* __restrict__ selO, char* lds) {
  char* ldsA = lds;           // [128 tok][32 d], stride 80
  char* ldsB = lds + 10240;   // [64 e][32 d], stride 80
  const int tid = threadIdx.x, l = tid & 63, w = tid >> 6;
  const int tokbase = (bidx >> 3) * 128;
  const int ebase   = (bidx & 7) * 64;
  const int wr = w & 1, wc = w >> 1;
  f32x4 acc[4][2] = {};
  const int arow = tid >> 1, ahalf = tid & 1;
  const int brow = tid >> 2, bgr = tid & 3;
  const int flat = tokbase + arow;
  const int bb = flat >> 11;
  const int hv = hidx[flat];
  const float* aS = head + ((size_t)bb * 2049 + hv) * 1024 + ahalf * 16;
  const float* bS = Wp + (size_t)(ebase + brow) * 1024 + bgr * 8;
  const int lo = (l & 15) * 80 + (l >> 4) * 16;
  for (int kb = 0; kb < 1024; kb += 32) {
    float4 a0 = *(const float4*)(aS + kb);
    float4 a1 = *(const float4*)(aS + kb + 4);
    float4 a2 = *(const float4*)(aS + kb + 8);
    float4 a3 = *(const float4*)(aS + kb + 12);
    float4 b0 = *(const float4*)(bS + kb);
    float4 b1 = *(const float4*)(bS + kb + 4);
    *(bf16x8*)(ldsA + arow * 80 + ahalf * 32)      = cvt8(a0, a1);
    *(bf16x8*)(ldsA + arow * 80 + ahalf * 32 + 16) = cvt8(a2, a3);
    *(bf16x8*)(ldsB + brow * 80 + bgr * 16)        = cvt8(b0, b1);
    __syncthreads();
    bf16x8 aF[4], bF[2];
#pragma unroll
    for (int i = 0; i < 4; ++i) aF[i] = *(bf16x8*)(ldsA + (wr * 64 + i * 16) * 80 + lo);
#pragma unroll
    for (int j = 0; j < 2; ++j) bF[j] = *(bf16x8*)(ldsB + (wc * 32 + j * 16) * 80 + lo);
#pragma unroll
    for (int i = 0; i < 4; ++i)
#pragma unroll
      for (int j = 0; j < 2; ++j)
        acc[i][j] = __builtin_amdgcn_mfma_f32_16x16x32_bf16(aF[i], bF[j], acc[i][j], 0, 0, 0);
    __syncthreads();
  }
#pragma unroll
  for (int i = 0; i < 4; ++i)
#pragma unroll
    for (int j = 0; j < 2; ++j)
#pragma unroll
      for (int r = 0; r < 4; ++r) {
        int tg = tokbase + wr * 64 + i * 16 + (l >> 4) * 4 + r;
        int eg = ebase + wc * 32 + j * 16 + (l & 15);
        selO[(size_t)tg * DLBL + eg] = (bf16)(acc[i][j][r] + bv[eg]);
      }
}

__global__ __launch_bounds__(256) void prep_k(const float* __restrict__ W,
                                              bf16* __restrict__ Wb,
                                              const float* __restrict__ dep_W,
                                              const float* __restrict__ dep,
                                              const float* __restrict__ dep_b,
                                              bf16* __restrict__ depT,
                                              const float* __restrict__ head,
                                              const int* __restrict__ hidx,
                                              const float* __restrict__ head_W,
                                              const float* __restrict__ head_b,
                                              bf16* __restrict__ selB) {
  __shared__ char lds[15360];
  const int b = blockIdx.x;
  if (b < 256) {
    projA_body(b, dep_W, dep, dep_b, depT, lds);
  } else if (b < 512) {
    projB_body(b - 256, head, hidx, head_W, head_b, selB, lds);
  } else {
    int i = (b - 512) * 256 + threadIdx.x;
    const float4* s = (const float4*)W + (size_t)i * 2;
    float4 a = s[0], c = s[1];
    *(bf16x8*)(Wb + (size_t)i * 8) = cvt8(a, c);
  }
}

// ---------------------------------------------------------------------------
// Kernel 4 v6: biaffine GEMM. 128d x 256tok block tile, 4 waves (2d x 2tok),
// wave tile 64d x 128tok = 4x8 frags (2.67 MFMA per ds_read, was 2.0).
// BK=32, 16 K-tiles, triple-buffered 72KB LDS -> 2 blocks/CU, counted
// vmcnt(6) + single barrier per K-tile, 2-tile prefetch lead, setprio MFMA.
//   Per K-tile per wave: 2 A-gl16 + 4 B-gl16 = 6 loads; 12 ds_read_b128;
//   32 MFMA. Phase t: {12 ds_read | stage t+2 | 32 MFMA | vmcnt(6) | bar}.
//   XCD map (proven r3/r5): xcd owns 25 combos, combo fast, tok slow.
// ---------------------------------------------------------------------------
__global__ __launch_bounds__(256, 2) void biaff_k(const bf16* __restrict__ Wb,
                                                  const bf16* __restrict__ sel,
                                                  const bf16* __restrict__ depT,
                                                  float* __restrict__ parts) {
  __shared__ char lds[73728];          // 3 x (A 8KB + B 16KB)
  const int tid = threadIdx.x, l = tid & 63, w = tid >> 6;   // w: 0..3

  // bijective XCD-aware decode: 3200 = 8 xcd * (25 combos * 16 tok), combo fast
  const int lin = blockIdx.x;
  const int xcd = lin & 7, idx = lin >> 3;   // idx 0..399
  const int sub = idx % 25;                  // fast
  const int bx  = idx / 25;                  // slow: tok tile 0..15
  const int combo = xcd * 25 + sub;          // 0..199
  const int n  = combo % 50;
  const int dz = combo / 50;                 // 0..3
  const int tokbase = bx * 256;
  const int dbase   = dz * 128;

  const int wd = w >> 1, wt = w & 1;         // wave tile: 64 d x 128 tok
  f32x4 acc[4][8] = {};

  // staging: lane -> row l>>2 within a 16-row group, stored chunk l&3;
  // source chunk pre-swizzled so the LDS image carries chunk ^= ((row>>1)&3)
  const int srow = l >> 2;
  const int schunk = ((l & 3) ^ ((l >> 3) & 3)) * 8;
  const bf16* aG = Wb  + ((size_t)(n * DLBL + dbase + w * 32 + srow)) * DLBL + schunk;
  const bf16* bG = sel + ((size_t)(tokbase + w * 64 + srow)) * DLBL + schunk;
  const int aOff = w * 2048;                 // w*32 rows * 64B
  const int bOff = 8192 + w * 4096;          // w*64 rows * 64B

  // frag reads: row = sub + lq, chunk = lh ^ ((lq>>1)&3)  (conflict-free, r4/r5)
  const int lq = l & 15, lh = l >> 4;
  const int ro = lh ^ ((lq >> 1) & 3);
  const char* rdA = lds + (wd * 64 + lq) * 64 + ro * 16;
  const char* rdB = lds + 8192 + (wt * 128 + lq) * 64 + ro * 16;

#define STG(T) do { \
    const bf16* a_ = aG + (T) * 32; \
    const bf16* b_ = bG + (T) * 32; \
    char* la_ = lds + ((T) % 3) * 24576 + aOff; \
    char* lb_ = lds + ((T) % 3) * 24576 + bOff; \
    gl16(a_, la_);            gl16(a_ + 16 * DLBL, la_ + 1024); \
    gl16(b_, lb_);            gl16(b_ + 16 * DLBL, lb_ + 1024); \
    gl16(b_ + 32 * DLBL, lb_ + 2048); gl16(b_ + 48 * DLBL, lb_ + 3072); \
  } while (0)
#define WAITV(N) asm volatile("s_waitcnt vmcnt(" #N ")" ::: "memory")
#define PHASE(T, DOSTG, DOWV6, DOWV0, DOBAR) do { \
    const char* cA = rdA + ((T) % 3) * 24576; \
    const char* cB = rdB + ((T) % 3) * 24576; \
    bf16x8 aF[4], bF[8]; \
    _Pragma("unroll") \
    for (int i = 0; i < 4; ++i) aF[i] = *(const bf16x8*)(cA + i * 1024); \
    _Pragma("unroll") \
    for (int j = 0; j < 8; ++j) bF[j] = *(const bf16x8*)(cB + j * 1024); \
    if (DOSTG) STG((T) + 2); \
    __builtin_amdgcn_s_setprio(1); \
    _Pragma("unroll") \
    for (int i = 0; i < 4; ++i) \
      _Pragma("unroll") \
      for (int j = 0; j < 8; ++j) \
        acc[i][j] = __builtin_amdgcn_mfma_f32_16x16x32_bf16(aF[i], bF[j], acc[i][j], 0, 0, 0); \
    __builtin_amdgcn_s_setprio(0); \
    if (DOWV6) WAITV(6); \
    if (DOWV0) WAITV(0); \
    if (DOBAR) __builtin_amdgcn_s_barrier(); \
  } while (0)

  // prologue: stage tiles 0,1 (12 loads/wave); certify tile 0 (drain to 6)
  STG(0); STG(1);
  WAITV(6);
  __builtin_amdgcn_s_barrier();

  PHASE(0, 1, 1, 0, 1);  PHASE(1, 1, 1, 0, 1);  PHASE(2, 1, 1, 0, 1);
  PHASE(3, 1, 1, 0, 1);  PHASE(4, 1, 1, 0, 1);  PHASE(5, 1, 1, 0, 1);
  PHASE(6, 1, 1, 0, 1);  PHASE(7, 1, 1, 0, 1);  PHASE(8, 1, 1, 0, 1);
  PHASE(9, 1, 1, 0, 1);  PHASE(10, 1, 1, 0, 1); PHASE(11, 1, 1, 0, 1);
  PHASE(12, 1, 1, 0, 1); PHASE(13, 1, 1, 0, 1);
  PHASE(14, 0, 0, 1, 1);                      // no stage; certify tile 15
  PHASE(15, 0, 0, 0, 0);                      // final tile, no sync needed

#undef PHASE
#undef WAITV
#undef STG

  // ---- epilogue: H[d,t] * depT[d,t], reduce over the wave's 64 d ----
  float p[8] = {0.f, 0.f, 0.f, 0.f, 0.f, 0.f, 0.f, 0.f};
#pragma unroll
  for (int j = 0; j < 8; ++j) {
    const int tg = tokbase + wt * 128 + j * 16 + lq;
#pragma unroll
    for (int i = 0; i < 4; ++i)
#pragma unroll
      for (int r = 0; r < 4; ++r) {
        int dg = dbase + wd * 64 + i * 16 + lh * 4 + r;
        p[j] += acc[i][j][r] * (float)depT[(size_t)dg * NTOK + tg];
      }
  }
#pragma unroll
  for (int j = 0; j < 8; ++j) {
    p[j] += __shfl_xor(p[j], 16);
    p[j] += __shfl_xor(p[j], 32);
  }
  if (l < 16) {
#pragma unroll
    for (int j = 0; j < 8; ++j) {
      int tg = tokbase + wt * 128 + j * 16 + l;
      parts[(size_t)(dz * 2 + wd) * 204800 + (size_t)tg * NLAB + n] = p[j];
    }
  }
}

// ---------------------------------------------------------------------------
// Kernel 5: sum the 8 d-partials + bias -> logits [4096][50] f32
// ---------------------------------------------------------------------------
__global__ __launch_bounds__(256) void fin_k(const float* __restrict__ parts,
                                             const float* __restrict__ bias,
                                             float* __restrict__ out) {
  int i = blockIdx.x * 256 + threadIdx.x;
  float v = 0.f;
#pragma unroll
  for (int q = 0; q < 8; ++q) v += parts[(size_t)q * 204800 + i];
  out[i] = v + bias[i % NLAB];
}

// ---------------------------------------------------------------------------
extern "C" void kernel_launch(void* const* d_in, const int* in_sizes, int n_in,
                              void* d_out, int out_size, void* d_ws, size_t ws_size,
                              hipStream_t stream) {
  const float* dep    = (const float*)d_in[0];
  const float* head   = (const float*)d_in[1];
  const int*   hidx   = (const int*)d_in[2];
  const float* dep_W  = (const float*)d_in[4];
  const float* dep_b  = (const float*)d_in[5];
  const float* head_W = (const float*)d_in[6];
  const float* head_b = (const float*)d_in[7];
  const float* W      = (const float*)d_in[8];
  const float* bias   = (const float*)d_in[9];
  float* out = (float*)d_out;

  char* ws = (char*)d_ws;
  bf16*  Wb    = (bf16*)(ws);
  bf16*  depT  = (bf16*)(ws + 26214400);
  bf16*  selB  = (bf16*)(ws + 30408704);
  float* parts = (float*)(ws + 34603008);
  if (ws_size < (size_t)41156608) return;

  hipLaunchKernelGGL(prep_k, dim3(6912), dim3(256), 0, stream,
                     W, Wb, dep_W, dep, dep_b, depT, head, hidx, head_W, head_b, selB);
  hipLaunchKernelGGL(biaff_k, dim3(3200), dim3(256), 0, stream, Wb, selB, depT, parts);
  hipLaunchKernelGGL(fin_k, dim3(800), dim3(256), 0, stream, parts, bias, out);
}